// Round 6
// baseline (499.549 us; speedup 1.0000x reference)
//
#include <hip/hip_runtime.h>
#include <hip/hip_bf16.h>
#include <math.h>

// ---------------- problem constants ----------------
#define B_SZ 2048
#define D_SZ 1024
#define U_SZ 1024
#define L_SZ 3
#define NB 8
#define KAN_K (D_SZ + D_SZ * NB)     // 9216 (kk dim)
#define WCAT_K (L_SZ * U_SZ)         // 3072 (fused inner dim)
#define LSTM_K (D_SZ + U_SZ)         // 2048
#define LSTM_N (4 * U_SZ)            // 4096
#define COMB_K (U_SZ + L_SZ * U_SZ)  // 4096

typedef __attribute__((ext_vector_type(8))) short bhalf8_t;  // 8 bf16 in 4 VGPRs
typedef __attribute__((ext_vector_type(4))) float floatx4_t; // MFMA C/D

__device__ inline void async_copy16(const void* g, void* l) {
  __builtin_amdgcn_global_load_lds(
      (const __attribute__((address_space(1))) void*)g,
      (__attribute__((address_space(3))) void*)l, 16, 0, 0);
}

__device__ inline float fsig(float v) { return 1.f / (1.f + __expf(-v)); }
__device__ inline float ftanh(float v) { return 1.f - 2.f / (__expf(2.f * v) + 1.f); }
__device__ inline unsigned short bfb(float v) {
  __hip_bfloat16 h = __float2bfloat16(v);
  return *(unsigned short*)&h;
}
__device__ inline unsigned int bfb2(float lo, float hi) {
  return (unsigned int)bfb(lo) | ((unsigned int)bfb(hi) << 16);
}

// =================================================================
// Kernel 1: prep + small transposes + Wcat interleave-convert.
// jobs: [0,8192) prep over B*D
//       [8192,9216)   lstm_kernel  [1024,4096] -> Bt1[:,0:1024]
//       [9216,10240)  lstm_rkernel [1024,4096] -> Bt1[:,1024:2048]
//       [10240,11264) combine_w    [4096,1024] -> Btc [1024,4096]
//       [11264,25088) Wcat[kk, l*1024+u] = bf16(Wkan_l[kk,u]) (elementwise)
// =================================================================
__global__ __launch_bounds__(256) void prep_trans(
    const float* __restrict__ x, const float* __restrict__ h_prev,
    const float* __restrict__ lstm_k, const float* __restrict__ lstm_r,
    const float* __restrict__ comb_w, const float* __restrict__ base_w,
    const float* __restrict__ spline_w,
    __hip_bfloat16* __restrict__ A1, __hip_bfloat16* __restrict__ Akan,
    __hip_bfloat16* __restrict__ Bt1, __hip_bfloat16* __restrict__ Btc,
    __hip_bfloat16* __restrict__ Wcat) {
  __shared__ float tile[64][65];
  int bid = blockIdx.x;
  int tid = threadIdx.x;
  if (bid < 8192) {
    // ---- prep: bf16 casts + silu + B-spline bases ----
    int idx = bid * 256 + tid;  // over B*D
    int b = idx >> 10, d = idx & 1023;
    float xv = x[idx];
    float hv = h_prev[idx];
    A1[(size_t)b * LSTM_K + d] = __float2bfloat16(xv);
    A1[(size_t)b * LSTM_K + D_SZ + d] = __float2bfloat16(hv);
    float sg = 1.0f / (1.0f + __expf(-xv));
    Akan[(size_t)b * KAN_K + d] = __float2bfloat16(xv * sg);
    float t[12];
#pragma unroll
    for (int i = 0; i < 12; ++i) t[i] = (float)(-1.0 + 0.4 * (double)(i - 3));
    float bb[11];
#pragma unroll
    for (int j = 0; j < 11; ++j) bb[j] = (xv >= t[j] && xv < t[j + 1]) ? 1.0f : 0.0f;
#pragma unroll
    for (int p = 1; p <= 3; ++p) {
#pragma unroll
      for (int j = 0; j + p < 11; ++j) {
        float invl = 1.0f / (t[j + p] - t[j]);          // compile-time folded
        float invr = 1.0f / (t[j + p + 1] - t[j + 1]);  // compile-time folded
        bb[j] = (xv - t[j]) * invl * bb[j] + (t[j + p + 1] - xv) * invr * bb[j + 1];
      }
    }
    unsigned short o[8];
#pragma unroll
    for (int j = 0; j < 8; ++j) o[j] = bfb(bb[j]);
    *(uint4*)(Akan + (size_t)b * KAN_K + D_SZ + d * 8) = *(uint4*)o;
    return;
  }
  if (bid >= 11264) {
    // ---- Wcat interleave: coalesced elementwise f32->bf16 ----
    int e0 = (bid - 11264) * 2048 + tid * 8;  // 8 elems/thread
    int kk = e0 / WCAT_K;
    int col = e0 - kk * WCAT_K;
    int l = col >> 10, u = col & 1023;
    const float* srow = (kk < 1024)
        ? base_w + ((size_t)l << 20) + (size_t)kk * 1024 + u
        : spline_w + (size_t)l * 8388608 + (size_t)(kk - 1024) * 1024 + u;
    float4 v0 = *(const float4*)(srow);
    float4 v1 = *(const float4*)(srow + 4);
    uint4 q;
    q.x = bfb2(v0.x, v0.y);
    q.y = bfb2(v0.z, v0.w);
    q.z = bfb2(v1.x, v1.y);
    q.w = bfb2(v1.z, v1.w);
    *(uint4*)(Wcat + (size_t)kk * WCAT_K + col) = q;
    return;
  }
  // ---- transpose path (small weights only) ----
  int id = bid - 8192;
  const float* src;
  __hip_bfloat16* dst;
  int srcLd, dstLd, gxs;
  if (id < 1024) {            // lstm_kernel -> Bt1[:,0:1024]
    src = lstm_k; dst = Bt1; srcLd = 4096; dstLd = 2048; gxs = 6;
  } else if (id < 2048) {     // lstm_rkernel -> Bt1[:,1024:2048]
    id -= 1024; src = lstm_r; dst = Bt1 + 1024; srcLd = 4096; dstLd = 2048; gxs = 6;
  } else {                    // combine_w [4096,1024] -> Btc [1024,4096]
    id -= 2048; src = comb_w; dst = Btc; srcLd = 1024; dstLd = 4096; gxs = 4;
  }
  int n0 = (id & ((1 << gxs) - 1)) * 64;
  int k0 = (id >> gxs) * 64;
  int c4 = (tid & 15) * 4;
  int r0 = tid >> 4;
#pragma unroll
  for (int i = 0; i < 4; ++i) {
    int r = r0 + i * 16;
    const float4 v = *(const float4*)(src + (size_t)(k0 + r) * srcLd + n0 + c4);
    tile[r][c4 + 0] = v.x;
    tile[r][c4 + 1] = v.y;
    tile[r][c4 + 2] = v.z;
    tile[r][c4 + 3] = v.w;
  }
  __syncthreads();
  int kg = (tid & 15) * 4;
  int nn = tid >> 4;
#pragma unroll
  for (int i = 0; i < 4; ++i) {
    int n = nn + i * 16;
    ushort4 w;
    w.x = bfb(tile[kg + 0][n]);
    w.y = bfb(tile[kg + 1][n]);
    w.z = bfb(tile[kg + 2][n]);
    w.w = bfb(tile[kg + 3][n]);
    *(ushort4*)(dst + (size_t)(n0 + n) * dstLd + k0 + kg) = w;
  }
}

// =================================================================
// GEMM core. LDS buffer is passed in from the kernel (ONE static
// __shared__ per kernel — round-5 lesson: per-instantiation static
// __shared__ arrays are NOT unioned; two instantiations cost 64 KB
// and halve occupancy).
// EPI: 0 = f32 store, 1 = bf16 store, 3 = f32 + bias + sum of 6 partials
// =================================================================
template <int EPI>
__device__ __forceinline__ void gemm_core(
    char* __restrict__ lds,
    const __hip_bfloat16* __restrict__ A, int lda,
    const __hip_bfloat16* __restrict__ Bt, int ldb,
    void* __restrict__ Cout, int ldc, int m0, int n0, int kBeg, int kEnd,
    const float* __restrict__ bias = nullptr,
    const float* __restrict__ red = nullptr, size_t redStride = 0) {
  char* ldsA = lds;
  char* ldsB = lds + 16384;
  int tid = threadIdx.x;
  int lane = tid & 63;
  int wave = tid >> 6;
  int wm = wave >> 1, wn = wave & 1;
  int q = lane >> 4, l16 = lane & 15;

  floatx4_t acc[4][4];
#pragma unroll
  for (int i = 0; i < 4; ++i)
#pragma unroll
    for (int j = 0; j < 4; ++j) acc[i][j] = (floatx4_t){0.f, 0.f, 0.f, 0.f};

  const __hip_bfloat16* Ab = A + (size_t)m0 * lda;
  const __hip_bfloat16* Bb = Bt + (size_t)n0 * ldb;

  for (int k0 = kBeg; k0 < kEnd; k0 += 64) {
#pragma unroll
    for (int it = 0; it < 4; ++it) {
      int L = tid + it * 256;
      int n = L >> 3;
      int c = (L & 7) ^ (n & 7);
      async_copy16((const char*)(Ab + (size_t)n * lda + k0) + c * 16, ldsA + L * 16);
    }
#pragma unroll
    for (int it = 0; it < 4; ++it) {
      int L = tid + it * 256;
      int n = L >> 3;
      int c = (L & 7) ^ (n & 7);
      async_copy16((const char*)(Bb + (size_t)n * ldb + k0) + c * 16, ldsB + L * 16);
    }
    __syncthreads();
#pragma unroll
    for (int s = 0; s < 2; ++s) {
      bhalf8_t af[4], bf[4];
#pragma unroll
      for (int mt = 0; mt < 4; ++mt) {
        int row = wm * 64 + mt * 16 + l16;
        int p = (s * 4 + q) ^ (row & 7);
        af[mt] = *(const bhalf8_t*)(ldsA + row * 128 + p * 16);
      }
#pragma unroll
      for (int nt = 0; nt < 4; ++nt) {
        int row = wn * 64 + nt * 16 + l16;
        int p = (s * 4 + q) ^ (row & 7);
        bf[nt] = *(const bhalf8_t*)(ldsB + row * 128 + p * 16);
      }
#pragma unroll
      for (int mt = 0; mt < 4; ++mt)
#pragma unroll
        for (int nt = 0; nt < 4; ++nt)
          acc[mt][nt] = __builtin_amdgcn_mfma_f32_16x16x32_bf16(af[mt], bf[nt], acc[mt][nt], 0, 0, 0);
    }
    __syncthreads();
  }
  // epilogue: C/D layout col=lane&15, row=(lane>>4)*4+reg
#pragma unroll
  for (int mt = 0; mt < 4; ++mt) {
#pragma unroll
    for (int nt = 0; nt < 4; ++nt) {
      int ccol = n0 + wn * 64 + nt * 16 + l16;
#pragma unroll
      for (int i = 0; i < 4; ++i) {
        int crow = m0 + wm * 64 + mt * 16 + q * 4 + i;
        float v = acc[mt][nt][i];
        if (EPI == 0) {
          ((float*)Cout)[(size_t)crow * ldc + ccol] = v;
        } else if (EPI == 1) {
          ((__hip_bfloat16*)Cout)[(size_t)crow * ldc + ccol] = __float2bfloat16(v);
        } else {
          v += bias[ccol];
          size_t off = (size_t)crow * ldc + ccol;
#pragma unroll
          for (int p = 0; p < 6; ++p) v += red[redStride * p + off];
          ((float*)Cout)[off] = v;
        }
      }
    }
  }
}

// =================================================================
// Kernel 2: Wfused GEMM (long, first) + LSTM z GEMM in one dispatch.
// jobs [0,576):  Wfsum^T[1024,9216] = Btc[:,1024:4096] @ Wcat^T (K=3072,48 it)
// jobs [576,1088): z = A1 @ Bt1^T (M=2048,N=4096,K=2048, 32 it)
// =================================================================
__global__ __launch_bounds__(256) void gemm_multi(
    const __hip_bfloat16* __restrict__ A1, const __hip_bfloat16* __restrict__ Bt1,
    const __hip_bfloat16* __restrict__ Btc, const __hip_bfloat16* __restrict__ Wcat,
    float* __restrict__ z, __hip_bfloat16* __restrict__ Wfsum) {
  __shared__ __align__(16) char lds[32768];
  int id = blockIdx.x;
  if (id < 576) {
    int m0 = (id / 72) * 128;   // uo tiles: 8
    int n0 = (id % 72) * 128;   // kk tiles: 72
    gemm_core<1>(lds, Btc + 1024, COMB_K, Wcat, WCAT_K, Wfsum, KAN_K,
                 m0, n0, 0, WCAT_K);
  } else {
    int j2 = id - 576;
    int n0 = (j2 & 31) * 128;
    int m0 = (j2 >> 5) * 128;
    gemm_core<0>(lds, A1, LSTM_K, Bt1, LSTM_K, z, LSTM_N, m0, n0, 0, LSTM_K);
  }
}

// =================================================================
// Kernel 3: kan GEMM split-K=6 (first) + LSTM gates (backfill).
// jobs [0,768): Pkan[sk] = Akan @ Wfsum^T over K-chunk sk (1536 each, 24 it)
// jobs [768,8960): gates over B*U -> h, c, Hb(bf16)
// =================================================================
__global__ __launch_bounds__(256) void kan_gates(
    const __hip_bfloat16* __restrict__ Akan, const __hip_bfloat16* __restrict__ Wfsum,
    const float* __restrict__ z, const float* __restrict__ c_prev,
    const float* __restrict__ bias, float* __restrict__ Pkan,
    float* __restrict__ h_out, float* __restrict__ c_out,
    __hip_bfloat16* __restrict__ Hb) {
  __shared__ __align__(16) char lds[32768];
  int id = blockIdx.x;
  if (id < 768) {
    int sk = id >> 7;
    int rem = id & 127;
    int n0 = (rem & 7) * 128;   // uo tiles: 8
    int m0 = (rem >> 3) * 128;  // b tiles: 16
    gemm_core<0>(lds, Akan, KAN_K, Wfsum, KAN_K, Pkan + (size_t)sk * B_SZ * U_SZ, U_SZ,
                 m0, n0, sk * 1536, sk * 1536 + 1536);
    return;
  }
  int idx = (id - 768) * 256 + threadIdx.x;  // over B*U
  int b = idx >> 10, u = idx & 1023;
  const float* zr = z + (size_t)b * LSTM_N;
  float zi = zr[u] + bias[u];
  float zf = zr[U_SZ + u] + bias[U_SZ + u];
  float zg = zr[2 * U_SZ + u] + bias[2 * U_SZ + u];
  float zo = zr[3 * U_SZ + u] + bias[3 * U_SZ + u];
  float c = fsig(zf) * c_prev[idx] + fsig(zi) * ftanh(zg);
  float h = fsig(zo) * ftanh(c);
  h_out[idx] = h;
  c_out[idx] = c;
  Hb[idx] = __float2bfloat16(h);
}

// =================================================================
// Kernel 4: h-GEMM (M=2048,N=1024,K=1024) with fused epilogue:
// out = h @ Wc_top + Σ_p Pkan[p] + bias
// =================================================================
__global__ __launch_bounds__(256) void final_gemm(
    const __hip_bfloat16* __restrict__ Hb, const __hip_bfloat16* __restrict__ Btc,
    const float* __restrict__ Pkan, const float* __restrict__ comb_b,
    float* __restrict__ out) {
  __shared__ __align__(16) char lds[32768];
  int id = blockIdx.x;  // 128 blocks
  int n0 = (id & 7) * 128;
  int m0 = (id >> 3) * 128;
  gemm_core<3>(lds, Hb, U_SZ, Btc, COMB_K, out, U_SZ, m0, n0, 0, U_SZ,
               comb_b, Pkan, (size_t)B_SZ * U_SZ);
}

// ---------------- launcher ----------------
extern "C" void kernel_launch(void* const* d_in, const int* in_sizes, int n_in,
                              void* d_out, int out_size, void* d_ws, size_t ws_size,
                              hipStream_t stream) {
  const float* x        = (const float*)d_in[0];
  const float* h_prev   = (const float*)d_in[1];
  const float* c_prev   = (const float*)d_in[2];
  const float* lstm_k   = (const float*)d_in[3];
  const float* lstm_r   = (const float*)d_in[4];
  const float* lstm_b   = (const float*)d_in[5];
  const float* base_w   = (const float*)d_in[6];
  const float* spline_w = (const float*)d_in[7];
  const float* comb_w   = (const float*)d_in[8];
  const float* comb_b   = (const float*)d_in[9];
  float* out = (float*)d_out;  // [output | h | c], each B*U f32

  char* ws = (char*)d_ws;
  auto alloc = [&](size_t bytes) {
    char* p = ws;
    ws += (bytes + 255) & ~(size_t)255;
    return p;
  };
  __hip_bfloat16* A1    = (__hip_bfloat16*)alloc((size_t)B_SZ * LSTM_K * 2);   // 8MB
  __hip_bfloat16* Akan  = (__hip_bfloat16*)alloc((size_t)B_SZ * KAN_K * 2);    // 36MB
  __hip_bfloat16* Hb    = (__hip_bfloat16*)alloc((size_t)B_SZ * U_SZ * 2);     // 4MB
  __hip_bfloat16* Bt1   = (__hip_bfloat16*)alloc((size_t)LSTM_N * LSTM_K * 2); // 16MB
  __hip_bfloat16* Btc   = (__hip_bfloat16*)alloc((size_t)U_SZ * COMB_K * 2);   // 8MB
  __hip_bfloat16* Wcat  = (__hip_bfloat16*)alloc((size_t)KAN_K * WCAT_K * 2);  // 56.6MB
  __hip_bfloat16* Wfsum = (__hip_bfloat16*)alloc((size_t)U_SZ * KAN_K * 2);    // 18.9MB
  float* z              = (float*)alloc((size_t)B_SZ * LSTM_N * 4);            // 32MB
  float* Pkan           = (float*)alloc((size_t)6 * B_SZ * U_SZ * 4);          // 50.3MB

  // 1) prep + small transposes + Wcat interleave
  prep_trans<<<dim3(25088), 256, 0, stream>>>(x, h_prev, lstm_k, lstm_r, comb_w,
                                              base_w, spline_w, A1, Akan, Bt1, Btc, Wcat);
  // 2) Wfused GEMM + LSTM z GEMM
  gemm_multi<<<dim3(1088), 256, 0, stream>>>(A1, Bt1, Btc, Wcat, z, Wfsum);
  // 3) kan GEMM split-K=6 + gates
  kan_gates<<<dim3(8960), 256, 0, stream>>>(Akan, Wfsum, z, c_prev, lstm_b, Pkan,
                                            out + (size_t)B_SZ * U_SZ,
                                            out + 2 * (size_t)B_SZ * U_SZ, Hb);
  // 4) h-GEMM + partial-reduce + bias -> out
  final_gemm<<<dim3(128), 256, 0, stream>>>(Hb, Btc, Pkan, comb_b, out);
}